// Round 11
// baseline (336.359 us; speedup 1.0000x reference)
//
#include <hip/hip_runtime.h>

#define N_NODES 100000
#define N_EDGES 3200000
#define D 128
#define NB 782        // buckets of 128 destination nodes
#define BCAP 5120     // per-bucket entry capacity (mean 4093, sigma~64 -> +16 sigma)
#define STAGE 16      // entries staged per bucket = one 64B cacheline
#define QNODES 25000  // nodes per agg quarter-launch

typedef __attribute__((ext_vector_type(8))) short bf16x8;
typedef __attribute__((ext_vector_type(4))) float f32x4;

__device__ __forceinline__ float bf2f(unsigned short u) {
  return __uint_as_float(((unsigned)u) << 16);
}
__device__ __forceinline__ unsigned short f2bf(float f) {
  unsigned u = __float_as_uint(f);
  u += 0x7FFF + ((u >> 16) & 1);   // round-to-nearest-even
  return (unsigned short)(u >> 16);
}

// W[k][c] f32 -> wTg[c][k] bf16. 16 blocks (was 1 -> latency-serial).
__global__ void prep_w_kernel(const float* __restrict__ W, unsigned short* __restrict__ wTg) {
  int idx = blockIdx.x * 256 + threadIdx.x;  // 4096 threads
  int c = idx >> 5;                          // 32 threads per column
  int k0 = (idx & 31) * 4;
  unsigned short tmp[4];
#pragma unroll
  for (int j = 0; j < 4; j++) tmp[j] = f2bf(W[(size_t)(k0 + j) * D + c]);
  *(uint2*)(wTg + (size_t)c * D + k0) = *(uint2*)tmp;
}

// Pass A: partition edges into 782 dest-buckets; LDS-staged 64B-line flushes.
// int64/int32 detection folded in (per-block, 8KB L2-broadcast read).
__global__ __launch_bounds__(256) void partition_kernel(const void* __restrict__ edges,
                                                        int* __restrict__ gcur,
                                                        unsigned int* __restrict__ bstore) {
  __shared__ unsigned int stage[NB][STAGE];  // 50 KB
  __shared__ int scnt[NB];                   // 3.1 KB
  __shared__ int s_nz;
  if (threadIdx.x == 0) s_nz = 0;
  for (int i = threadIdx.x; i < NB; i += 256) scnt[i] = 0;
  __syncthreads();
  {  // detect: int64 iff odd 32-bit words all zero over first 2048 pairs
    int v = 0;
    const int* e32 = (const int*)edges;
    for (int i = threadIdx.x; i < 2048; i += 256) v |= e32[2 * i + 1];
    if (v) atomicOr(&s_nz, 1);
  }
  __syncthreads();
  const bool is64 = (s_nz == 0);
  int gstride = gridDim.x * blockDim.x;
  for (int base = blockIdx.x * blockDim.x; base < N_EDGES; base += gstride) {
    int e = base + threadIdx.x;
    if (e < N_EDGES) {
      int r, c;
      if (is64) {
        r = (int)((const long long*)edges)[e];
        c = (int)((const long long*)edges)[N_EDGES + e];
      } else {
        r = ((const int*)edges)[e];
        c = ((const int*)edges)[N_EDGES + e];
      }
      int b = r >> 7;
      unsigned ent = ((unsigned)(r & 127) << 17) | (unsigned)c;
      int pos = atomicAdd(&scnt[b], 1);
      if (pos < STAGE) {
        stage[b][pos] = ent;
      } else {  // overflow slow-path: per-entry append
        int gp = atomicAdd(&gcur[b], 1);
        if (gp < BCAP) bstore[(size_t)b * BCAP + gp] = ent;
      }
    }
    __syncthreads();
    for (int b = threadIdx.x; b < NB; b += 256) {
      if (scnt[b] >= STAGE) {
        int gp = atomicAdd(&gcur[b], STAGE);
        if (gp + STAGE <= BCAP) {
          uint4* dst = (uint4*)&bstore[(size_t)b * BCAP + gp];
          uint4* src = (uint4*)&stage[b][0];
          dst[0] = src[0];
          dst[1] = src[1];
          dst[2] = src[2];
          dst[3] = src[3];
        } else {
          for (int k = 0; k < STAGE; k++)
            if (gp + k < BCAP) bstore[(size_t)b * BCAP + gp + k] = stage[b][k];
        }
        scnt[b] = 0;
      }
    }
    __syncthreads();
  }
  for (int b = threadIdx.x; b < NB; b += 256) {
    int n = scnt[b];
    if (n > STAGE) n = STAGE;
    if (n > 0) {
      int gp = atomicAdd(&gcur[b], n);
      for (int k = 0; k < n; k++)
        if (gp + k < BCAP) bstore[(size_t)b * BCAP + gp + k] = stage[b][k];
    }
  }
}

// Pass B: per-bucket 128-key counting sort (1024-key src-range variant was a
// measured null, R10) -> start/cnt/dinv + in-place src-col scatter.
__global__ __launch_bounds__(256) void bucket_kernel(const int* __restrict__ gcur,
                                                     unsigned int* __restrict__ bstore,
                                                     int* __restrict__ cnt,
                                                     int* __restrict__ start,
                                                     float* __restrict__ dinv) {
  __shared__ unsigned int ent[BCAP];  // 20 KB
  __shared__ int lcnt[128];
  __shared__ int s[128];
  __shared__ int loffs[128];
  int b = blockIdx.x, tid = threadIdx.x;
  size_t base = (size_t)b * BCAP;
  int m = gcur[b];
  if (m > BCAP) m = BCAP;
  int nodes = N_NODES - b * 128;
  if (nodes > 128) nodes = 128;

  for (int i = tid; i < m; i += 256) ent[i] = bstore[base + i];
  if (tid < 128) lcnt[tid] = 0;
  __syncthreads();
  for (int i = tid; i < m; i += 256) atomicAdd(&lcnt[ent[i] >> 17], 1);
  __syncthreads();
  if (tid < 128) s[tid] = lcnt[tid];
  __syncthreads();
#pragma unroll
  for (int off = 1; off < 128; off <<= 1) {
    int v = (tid < 128 && tid >= off) ? s[tid - off] : 0;
    __syncthreads();
    if (tid < 128) s[tid] += v;
    __syncthreads();
  }
  if (tid < nodes) {
    int st = (tid == 0) ? 0 : s[tid - 1];
    int node = b * 128 + tid;
    start[node] = (int)base + st;
    cnt[node] = lcnt[tid];
    dinv[node] = rsqrtf((float)(lcnt[tid] + 1));  // +1 self-loop
    loffs[tid] = st;
  }
  __syncthreads();
  for (int i = tid; i < m; i += 256) {
    unsigned u = ent[i];
    int lr = u >> 17;
    int pos = atomicAdd(&loffs[lr], 1);
    bstore[base + pos] = u & 0x1FFFF;  // store src col only
  }
}

// MFMA gemm: y[n][d] = bf16(dinv[n] * (x@W)[n][d]). 64 rows/block, 4 waves.
__global__ __launch_bounds__(256) void gemm_mfma_kernel(const float* __restrict__ x,
                                                        const unsigned short* __restrict__ wTg,
                                                        const float* __restrict__ dinv,
                                                        unsigned short* __restrict__ y) {
  __shared__ unsigned short xs[64 * 136];   // 17.4 KB
  __shared__ unsigned short wls[128 * 136]; // 34.8 KB
  int tid = threadIdx.x;
  int row0 = blockIdx.x * 64;
  {  // stage W^T (bf16, coalesced)
    int c = tid >> 1, h = tid & 1;
    const uint4* src = (const uint4*)(wTg + c * D + h * 64);
    uint4* dst = (uint4*)(wls + c * 136 + h * 64);
#pragma unroll
    for (int i = 0; i < 8; i++) dst[i] = src[i];
  }
  {  // stage x rows -> bf16
    int rx = tid >> 2, q = tid & 3;
    int r = row0 + rx;
    if (r > N_NODES - 1) r = N_NODES - 1;
    const float4* src = (const float4*)(x + (size_t)r * D + q * 32);
    uint4* dst = (uint4*)(xs + rx * 136 + q * 32);
#pragma unroll
    for (int i = 0; i < 4; i++) {
      float4 fa = src[2 * i], fb = src[2 * i + 1];
      uint4 p;
      p.x = (unsigned)f2bf(fa.x) | ((unsigned)f2bf(fa.y) << 16);
      p.y = (unsigned)f2bf(fa.z) | ((unsigned)f2bf(fa.w) << 16);
      p.z = (unsigned)f2bf(fb.x) | ((unsigned)f2bf(fb.y) << 16);
      p.w = (unsigned)f2bf(fb.z) | ((unsigned)f2bf(fb.w) << 16);
      dst[i] = p;
    }
  }
  __syncthreads();
  int w = tid >> 6, l = tid & 63;
  int g = l >> 4, ln = l & 15;
  bf16x8 af[4];
#pragma unroll
  for (int kt = 0; kt < 4; kt++)
    af[kt] = *(const bf16x8*)(xs + (w * 16 + ln) * 136 + kt * 32 + g * 8);
  int rbase = row0 + w * 16 + 4 * g;
  float dv[4];
#pragma unroll
  for (int j = 0; j < 4; j++) {
    int r = rbase + j;
    dv[j] = dinv[r < N_NODES ? r : N_NODES - 1];
  }
#pragma unroll
  for (int ct = 0; ct < 8; ct++) {
    f32x4 acc = {0.f, 0.f, 0.f, 0.f};
#pragma unroll
    for (int kt = 0; kt < 4; kt++) {
      bf16x8 bf = *(const bf16x8*)(wls + (ct * 16 + ln) * 136 + kt * 32 + g * 8);
      acc = __builtin_amdgcn_mfma_f32_16x16x32_bf16(af[kt], bf, acc, 0, 0, 0);
    }
#pragma unroll
    for (int j = 0; j < 4; j++) {
      int r = rbase + j;
      if (r < N_NODES) y[(size_t)r * D + ct * 16 + ln] = f2bf(dv[j] * acc[j]);
    }
  }
}

// One wave per node; quarter-waves: 4 edges per load inst, uint4 (8 dims)/lane.
// Template Q gives each quarter-launch a DISTINCT kernel name so rocprof's
// top-5 can reveal second-tier kernels (agg replicas saturated the view).
template <int Q>
__global__ __launch_bounds__(256) void agg_ln_kernel(
    const unsigned short* __restrict__ y, const unsigned int* __restrict__ csr,
    const int* __restrict__ start, const int* __restrict__ cnt,
    const float* __restrict__ dinv, const float* __restrict__ bias,
    const float* __restrict__ gamma, const float* __restrict__ beta,
    float* __restrict__ out) {
  int wid = threadIdx.x >> 6, lane = threadIdx.x & 63;
  int node = Q * QNODES + blockIdx.x * 4 + wid;
  int q = lane >> 4, hl = lane & 15;
  int s = start[node];
  int n = cnt[node];
  float a0 = 0.f, a1 = 0.f, a2 = 0.f, a3 = 0.f, a4 = 0.f, a5 = 0.f, a6 = 0.f, a7 = 0.f;
  const unsigned short* yq = y + hl * 8;
#define ACC(V)                                       \
  a0 += __uint_as_float((V).x << 16);                \
  a1 += __uint_as_float((V).x & 0xFFFF0000u);        \
  a2 += __uint_as_float((V).y << 16);                \
  a3 += __uint_as_float((V).y & 0xFFFF0000u);        \
  a4 += __uint_as_float((V).z << 16);                \
  a5 += __uint_as_float((V).z & 0xFFFF0000u);        \
  a6 += __uint_as_float((V).w << 16);                \
  a7 += __uint_as_float((V).w & 0xFFFF0000u);
  for (int j = 0; j < n; j += 64) {
    int m = n - j;
    if (m > 64) m = 64;
    int cj = (j + lane < n) ? (int)csr[s + j + lane] : 0;
    int t = 0;
    for (; t + 15 < m; t += 16) {  // 4 loads = 16 edges in flight
      int e0 = __shfl(cj, t + q);
      int e1 = __shfl(cj, t + 4 + q);
      int e2 = __shfl(cj, t + 8 + q);
      int e3 = __shfl(cj, t + 12 + q);
      uint4 v0 = *(const uint4*)(yq + (size_t)e0 * D);
      uint4 v1 = *(const uint4*)(yq + (size_t)e1 * D);
      uint4 v2 = *(const uint4*)(yq + (size_t)e2 * D);
      uint4 v3 = *(const uint4*)(yq + (size_t)e3 * D);
      ACC(v0) ACC(v1) ACC(v2) ACC(v3)
    }
    for (; t + 3 < m; t += 4) {
      int e0 = __shfl(cj, t + q);
      uint4 v0 = *(const uint4*)(yq + (size_t)e0 * D);
      ACC(v0)
    }
    int rem = m - t;
    if (rem > 0) {  // 1-3 tail edges: quarters < rem participate
      int sl = t + q;
      if (sl > m - 1) sl = m - 1;
      int e0 = __shfl(cj, sl);
      if (q < rem) {
        uint4 v0 = *(const uint4*)(yq + (size_t)e0 * D);
        ACC(v0)
      }
    }
  }
#define FOLD(A)            \
  A += __shfl_xor(A, 16);  \
  A += __shfl_xor(A, 32);
  FOLD(a0) FOLD(a1) FOLD(a2) FOLD(a3) FOLD(a4) FOLD(a5) FOLD(a6) FOLD(a7)
  // self-loop (all lanes add identical full value)
  uint4 sv = *(const uint4*)(yq + (size_t)node * D);
  ACC(sv)
  float di = dinv[node];
  float4 bi0 = *(const float4*)(bias + hl * 8);
  float4 bi1 = *(const float4*)(bias + hl * 8 + 4);
  float v0 = fmaf(di, a0, bi0.x), v1 = fmaf(di, a1, bi0.y);
  float v2 = fmaf(di, a2, bi0.z), v3 = fmaf(di, a3, bi0.w);
  float v4 = fmaf(di, a4, bi1.x), v5 = fmaf(di, a5, bi1.y);
  float v6 = fmaf(di, a6, bi1.z), v7 = fmaf(di, a7, bi1.w);
  float sum = ((v0 + v1) + (v2 + v3)) + ((v4 + v5) + (v6 + v7));
#pragma unroll
  for (int msk = 1; msk <= 8; msk <<= 1) sum += __shfl_xor(sum, msk);
  float mu = sum * (1.0f / 128.0f);
  float d0 = v0 - mu, d1 = v1 - mu, d2 = v2 - mu, d3 = v3 - mu;
  float d4 = v4 - mu, d5 = v5 - mu, d6 = v6 - mu, d7 = v7 - mu;
  float sq = ((d0 * d0 + d1 * d1) + (d2 * d2 + d3 * d3)) +
             ((d4 * d4 + d5 * d5) + (d6 * d6 + d7 * d7));
#pragma unroll
  for (int msk = 1; msk <= 8; msk <<= 1) sq += __shfl_xor(sq, msk);
  float rstd = rsqrtf(sq * (1.0f / 128.0f) + 1e-5f);
  if (q == 0) {
    float4 ga0 = *(const float4*)(gamma + hl * 8);
    float4 ga1 = *(const float4*)(gamma + hl * 8 + 4);
    float4 be0 = *(const float4*)(beta + hl * 8);
    float4 be1 = *(const float4*)(beta + hl * 8 + 4);
    float4 o0, o1;
    o0.x = fmaxf(fmaf(d0 * rstd, ga0.x, be0.x), 0.0f);
    o0.y = fmaxf(fmaf(d1 * rstd, ga0.y, be0.y), 0.0f);
    o0.z = fmaxf(fmaf(d2 * rstd, ga0.z, be0.z), 0.0f);
    o0.w = fmaxf(fmaf(d3 * rstd, ga0.w, be0.w), 0.0f);
    o1.x = fmaxf(fmaf(d4 * rstd, ga1.x, be1.x), 0.0f);
    o1.y = fmaxf(fmaf(d5 * rstd, ga1.y, be1.y), 0.0f);
    o1.z = fmaxf(fmaf(d6 * rstd, ga1.z, be1.z), 0.0f);
    o1.w = fmaxf(fmaf(d7 * rstd, ga1.w, be1.w), 0.0f);
    *(float4*)(out + (size_t)node * D + hl * 8) = o0;
    *(float4*)(out + (size_t)node * D + hl * 8 + 4) = o1;
  }
#undef ACC
#undef FOLD
}

extern "C" void kernel_launch(void* const* d_in, const int* in_sizes, int n_in,
                              void* d_out, int out_size, void* d_ws, size_t ws_size,
                              hipStream_t stream) {
  const float* x = (const float*)d_in[0];
  const void* edges = d_in[1];
  const float* W = (const float*)d_in[2];
  const float* b = (const float*)d_in[3];
  const float* gamma = (const float*)d_in[4];
  const float* beta = (const float*)d_in[5];
  float* out = (float*)d_out;

  char* w = (char*)d_ws;
  size_t off = 0;
  auto take = [&](size_t bytes) {
    size_t r = off;
    off += (bytes + 255) & ~(size_t)255;
    return r;
  };
  int* gcur = (int*)(w + take((size_t)NB * 4));
  int* cnt = (int*)(w + take((size_t)N_NODES * 4));
  int* start = (int*)(w + take((size_t)N_NODES * 4));
  float* dinv = (float*)(w + take((size_t)N_NODES * 4));
  unsigned short* wTg = (unsigned short*)(w + take((size_t)D * D * 2));     // 32 KB
  unsigned int* bstore = (unsigned int*)(w + take((size_t)NB * BCAP * 4));  // 16 MB
  unsigned short* y = (unsigned short*)(w + take((size_t)N_NODES * D * 2)); // 25.6 MB

  hipMemsetAsync(gcur, 0, (size_t)NB * 4, stream);
  prep_w_kernel<<<16, 256, 0, stream>>>(W, wTg);
  partition_kernel<<<768, 256, 0, stream>>>(edges, gcur, bstore);
  bucket_kernel<<<NB, 256, 0, stream>>>(gcur, bstore, cnt, start, dinv);
  gemm_mfma_kernel<<<(N_NODES + 63) / 64, 256, 0, stream>>>(x, wTg, dinv, y);
  agg_ln_kernel<0><<<QNODES / 4, 256, 0, stream>>>(y, bstore, start, cnt, dinv, b, gamma, beta, out);
  agg_ln_kernel<1><<<QNODES / 4, 256, 0, stream>>>(y, bstore, start, cnt, dinv, b, gamma, beta, out);
  agg_ln_kernel<2><<<QNODES / 4, 256, 0, stream>>>(y, bstore, start, cnt, dinv, b, gamma, beta, out);
  agg_ln_kernel<3><<<QNODES / 4, 256, 0, stream>>>(y, bstore, start, cnt, dinv, b, gamma, beta, out);
}